// Round 1
// 261.551 us; speedup vs baseline: 1.1085x; 1.1085x over previous
//
#include <hip/hip_runtime.h>
#include <math.h>

#define B_ROWS 4096
#define DIM    1024
#define NTOT   8192
#define NCLS   40
#define TILES  64   // 8192 / 128

typedef __attribute__((ext_vector_type(8))) short bf16x8;
typedef __attribute__((ext_vector_type(4))) float f32x4;

// ws layout (floats): [0]=nll_sum [1]=matdiff_sum [2]=sum_sq [3]=sxx [4]=syy
// [5]=smix(xy+yx) [6]=exp coeff 4/bw [7]=pad ; [8..1032)=colsum[1024] ;
// [1032..9224)=sq[8192] ; byte 36896+ : bf16 total[8192*1024]
#define WS_TOT_BYTE_OFF 36896

__device__ __forceinline__ unsigned short f2bf(float f) {
  unsigned int u = __float_as_uint(f);
  u += 0x7fffu + ((u >> 16) & 1u);   // RNE
  return (unsigned short)(u >> 16);
}

__device__ __forceinline__ void async16(const void* g, void* l) {
  __builtin_amdgcn_global_load_lds(
      (const __attribute__((address_space(1))) unsigned int*)g,
      (__attribute__((address_space(3))) unsigned int*)l, 16, 0, 0);
}

__device__ __forceinline__ float wave_sum(float v) {
  v += __shfl_xor(v, 32);
  v += __shfl_xor(v, 16);
  v += __shfl_xor(v, 8);
  v += __shfl_xor(v, 4);
  v += __shfl_xor(v, 2);
  v += __shfl_xor(v, 1);
  return v;
}

__global__ void init_k(float* W) {
  int t = blockIdx.x * blockDim.x + threadIdx.x;
  if (t < 1032) W[t] = 0.f;   // scalars + colsum
}

// 256 blocks x 256 threads (4 waves); wave owns whole rows -> no per-row syncs.
__global__ __launch_bounds__(256) void prep_k(const float* __restrict__ dense,
                                              const float* __restrict__ sparse,
                                              float* __restrict__ W,
                                              unsigned short* __restrict__ tot) {
  float* colsum = W + 8;
  float* sq = W + 1032;
  const int t = threadIdx.x;
  const int lane = t & 63, wave = t >> 6;
  __shared__ float colsum_l[1024];
  #pragma unroll
  for (int x = 0; x < 4; ++x) colsum_l[t * 4 + x] = 0.f;

  float c[4][4];
  #pragma unroll
  for (int j = 0; j < 4; ++j)
    #pragma unroll
    for (int x = 0; x < 4; ++x) c[j][x] = 0.f;

  float rowtot = 0.f;
  const int rbase = blockIdx.x * 32 + wave;   // 8 rows per wave, stride 4
  for (int i = 0; i < 8; ++i) {
    const int r = rbase + i * 4;
    const float* src = (r < B_ROWS) ? dense + (size_t)r * DIM
                                    : sparse + (size_t)(r - B_ROWS) * DIM;
    float sp = 0.f;
    #pragma unroll
    for (int j = 0; j < 4; ++j) {
      float4 v = ((const float4*)src)[lane + 64 * j];
      c[j][0] += v.x; c[j][1] += v.y; c[j][2] += v.z; c[j][3] += v.w;
      sp += v.x * v.x + v.y * v.y + v.z * v.z + v.w * v.w;
      ushort4 o;
      o.x = f2bf(v.x); o.y = f2bf(v.y); o.z = f2bf(v.z); o.w = f2bf(v.w);
      *(ushort4*)(tot + (size_t)r * DIM + (lane + 64 * j) * 4) = o;
    }
    sp = wave_sum(sp);
    if (lane == 0) { sq[r] = sp; rowtot += sp; }
  }
  if (lane == 0) atomicAdd(&W[2], rowtot);

  __syncthreads();
  #pragma unroll
  for (int j = 0; j < 4; ++j)
    #pragma unroll
    for (int x = 0; x < 4; ++x)
      atomicAdd(&colsum_l[4 * lane + 256 * j + x], c[j][x]);
  __syncthreads();
  #pragma unroll
  for (int x = 0; x < 4; ++x)
    atomicAdd(&colsum[t * 4 + x], colsum_l[t * 4 + x]);
}

// bandwidth: sumL2 = 2N*sum_sq - 2*||colsum||^2 ; store 4/bw
__global__ void bw_k(float* W) {
  const float* colsum = W + 8;
  const int t = threadIdx.x;
  float s = 0.f;
  for (int j = t; j < 1024; j += 256) { float v = colsum[j]; s += v * v; }
  s = wave_sum(s);
  __shared__ float red[4];
  if ((t & 63) == 0) red[t >> 6] = s;
  __syncthreads();
  if (t == 0) {
    double sumdots = (double)(red[0] + red[1] + red[2] + red[3]);
    double sum_sq = (double)W[2];
    double sumL2 = 2.0 * (double)NTOT * sum_sq - 2.0 * sumdots;
    double bwv = sumL2 / ((double)NTOT * (double)NTOT - (double)NTOT);
    W[6] = (float)(4.0 / bwv);
  }
}

__global__ __launch_bounds__(256) void nll_k(const float* __restrict__ pred,
                                             const int* __restrict__ tgt,
                                             float* __restrict__ W) {
  const int i = blockIdx.x * 256 + threadIdx.x;
  float v = pred[(size_t)i * NCLS + tgt[i]];
  v = wave_sum(v);
  __shared__ float red[4];
  if ((threadIdx.x & 63) == 0) red[threadIdx.x >> 6] = v;
  __syncthreads();
  if (threadIdx.x == 0) atomicAdd(&W[0], red[0] + red[1] + red[2] + red[3]);
}

// one wave per batch item: G = T T^T via MFMA (A-frag == B-frag), then ||I-G||_F
__global__ __launch_bounds__(256) void matdiff_k(const float* __restrict__ trans,
                                                 float* __restrict__ W) {
  const int t = threadIdx.x;
  const int lane = t & 63, wave = t >> 6;
  const int b = blockIdx.x * 4 + wave;
  const float* Tb = trans + (size_t)b * 4096;
  const int fr = lane & 15;
  const int k8 = (lane >> 4) * 8;
  bf16x8 frag[4][2];
  #pragma unroll
  for (int m = 0; m < 4; ++m) {
    #pragma unroll
    for (int kk = 0; kk < 2; ++kk) {
      const float* p = Tb + (size_t)(16 * m + fr) * 64 + kk * 32 + k8;
      float4 u0 = *(const float4*)p;
      float4 u1 = *(const float4*)(p + 4);
      bf16x8 f;
      f[0] = (short)f2bf(u0.x); f[1] = (short)f2bf(u0.y);
      f[2] = (short)f2bf(u0.z); f[3] = (short)f2bf(u0.w);
      f[4] = (short)f2bf(u1.x); f[5] = (short)f2bf(u1.y);
      f[6] = (short)f2bf(u1.z); f[7] = (short)f2bf(u1.w);
      frag[m][kk] = f;
    }
  }
  f32x4 acc[4][4];
  #pragma unroll
  for (int m = 0; m < 4; ++m)
    #pragma unroll
    for (int n = 0; n < 4; ++n) acc[m][n] = (f32x4)(0.f);
  #pragma unroll
  for (int kk = 0; kk < 2; ++kk)
    #pragma unroll
    for (int m = 0; m < 4; ++m)
      #pragma unroll
      for (int n = 0; n < 4; ++n)
        acc[m][n] = __builtin_amdgcn_mfma_f32_16x16x32_bf16(frag[m][kk], frag[n][kk],
                                                            acc[m][n], 0, 0, 0);
  float s = 0.f;
  const int crow = (lane >> 4) * 4;
  #pragma unroll
  for (int m = 0; m < 4; ++m)
    #pragma unroll
    for (int n = 0; n < 4; ++n)
      #pragma unroll
      for (int r = 0; r < 4; ++r) {
        int grow = 16 * m + crow + r;
        int gcol = 16 * n + fr;
        float g = acc[m][n][r];
        float d = (grow == gcol) ? (1.f - g) : (-g);
        s += d * d;
      }
  s = wave_sum(s);
  if (lane == 0) atomicAdd(&W[1], sqrtf(s));
}

// upper-triangular 128x128 tiles, XOR-swizzled LDS (T2, rule #21:
// linear LDS dest + inverse-swizzled global source + swizzled read).
// Round 1: T3-minimum double-buffer (stage next tile BEFORE compute of
// current, ONE barrier per K-step) + XCD-contiguous block remap (T1) +
// epilogue exp(smallest)+4 squarings instead of exp+4 sqrt.
__global__ __launch_bounds__(256) void gram_k(const unsigned short* __restrict__ tot,
                                              float* __restrict__ W) {
  __shared__ short As[2][128 * 64];
  __shared__ short Bs[2][128 * 64];
  __shared__ float sqA[128], sqB[128], red[4];
  const float* sq = W + 1032;
  const int t = threadIdx.x;
  const int lane = t & 63, wave = t >> 6;
  const int wr = wave >> 1, wc = wave & 1;

  // T1: XCD-contiguous remap; 2080 % 8 == 0 so simple chunking is bijective
  int p = (blockIdx.x & 7) * (2080 / 8) + (blockIdx.x >> 3);

  // decode linear block id -> (bi, bj), bi <= bj
  int bi = (int)((2 * TILES + 1 -
                  sqrtf((float)((2 * TILES + 1) * (2 * TILES + 1) - 8 * p))) * 0.5f);
  if (bi < 0) bi = 0;
  if (bi >= TILES) bi = TILES - 1;
  int start = bi * (2 * TILES - bi + 1) / 2;
  while (p < start) { --bi; start = bi * (2 * TILES - bi + 1) / 2; }
  while (p >= start + (TILES - bi)) { start += TILES - bi; ++bi; }
  const int bj = bi + (p - start);

  if (t < 128) sqA[t] = sq[bi * 128 + t];
  else         sqB[t - 128] = sq[bj * 128 + (t - 128)];
  const float cexp16 = W[6] * 0.0625f;   // c/16: exponent coeff of widest kernel

  f32x4 acc[4][4];
  #pragma unroll
  for (int m = 0; m < 4; ++m)
    #pragma unroll
    for (int n = 0; n < 4; ++n) acc[m][n] = (f32x4)(0.f);

  const int fr = lane & 15;

  // staging addresses: chunk = c4*256+t; row = chunk>>3; seg' = (chunk&7)^(row&7)
  const unsigned short* pA[4];
  const unsigned short* pB[4];
  int loff[4];
  #pragma unroll
  for (int c4 = 0; c4 < 4; ++c4) {
    int chunk = c4 * 256 + t;
    int row = chunk >> 3;
    int segp = (chunk & 7) ^ (row & 7);
    pA[c4] = tot + (size_t)(bi * 128 + row) * DIM + segp * 8;
    pB[c4] = tot + (size_t)(bj * 128 + row) * DIM + segp * 8;
    loff[c4] = chunk * 8;
  }
  // swizzled read byte-offset within a 128B row: colb ^ ((row&7)<<4);
  // row&7 == fr&7 for all fragment rows (wr*64+16m multiple of 8)
  const int swz = (fr & 7) << 4;

  // prologue: stage K-tile 0 into buffer 0, drain, barrier
  #pragma unroll
  for (int c4 = 0; c4 < 4; ++c4) {
    async16(pA[c4], &As[0][loff[c4]]);
    async16(pB[c4], &Bs[0][loff[c4]]);
  }
  __syncthreads();

  for (int kt = 0; kt < 16; ++kt) {
    const int cur = kt & 1;
    // issue next-tile loads FIRST so they fly under this tile's compute;
    // target buffer was last read at kt-1, barrier already passed -> safe
    if (kt < 15) {
      #pragma unroll
      for (int c4 = 0; c4 < 4; ++c4) {
        async16(pA[c4] + (kt + 1) * 64, &As[cur ^ 1][loff[c4]]);
        async16(pB[c4] + (kt + 1) * 64, &Bs[cur ^ 1][loff[c4]]);
      }
    }
    const char* baseA = (const char*)&As[cur][0];
    const char* baseB = (const char*)&Bs[cur][0];
    #pragma unroll
    for (int kk = 0; kk < 2; ++kk) {
      const int colb = kk * 64 + (lane >> 4) * 16;
      const int cswz = colb ^ swz;
      bf16x8 a[4], b[4];
      #pragma unroll
      for (int m = 0; m < 4; ++m)
        a[m] = *(const bf16x8*)(baseA + (wr * 64 + 16 * m + fr) * 128 + cswz);
      #pragma unroll
      for (int n = 0; n < 4; ++n)
        b[n] = *(const bf16x8*)(baseB + (wc * 64 + 16 * n + fr) * 128 + cswz);
      #pragma unroll
      for (int m = 0; m < 4; ++m)
        #pragma unroll
        for (int n = 0; n < 4; ++n)
          acc[m][n] = __builtin_amdgcn_mfma_f32_16x16x32_bf16(a[m], b[n],
                                                              acc[m][n], 0, 0, 0);
    }
    // single barrier per K-step: compiler drains vmcnt (next tile landed)
    // and lgkmcnt; all waves done reading buf[cur] -> it becomes stage target
    __syncthreads();
  }

  // epilogue: l2 -> 5-kernel sum. k_i = exp(-l2*c/2^i); compute smallest
  // exponent (i=4) once, then 4 squarings (full-rate mul, not 1/4-rate sqrt)
  float s = 0.f;
  const int crow = (lane >> 4) * 4;
  #pragma unroll
  for (int m = 0; m < 4; ++m) {
    #pragma unroll
    for (int n = 0; n < 4; ++n) {
      #pragma unroll
      for (int r = 0; r < 4; ++r) {
        int il = wr * 64 + 16 * m + crow + r;
        int jl = wc * 64 + 16 * n + fr;
        float l2 = sqA[il] + sqB[jl] - 2.f * acc[m][n][r];
        l2 = fmaxf(l2, 0.f);
        float k4 = __expf(-l2 * cexp16);
        float k3 = k4 * k4;
        float k2 = k3 * k3;
        float k1 = k2 * k2;
        float k0 = k1 * k1;
        s += k0 + k1 + k2 + k3 + k4;
      }
    }
  }
  s = wave_sum(s);
  if (lane == 0) red[wave] = s;
  __syncthreads();
  if (t == 0) {
    float ts = red[0] + red[1] + red[2] + red[3];
    int idx; float wgt;
    if (bi == bj)      { idx = (bi < 32) ? 3 : 4; wgt = 1.f; }
    else if (bj < 32)  { idx = 3; wgt = 2.f; }
    else if (bi >= 32) { idx = 4; wgt = 2.f; }
    else               { idx = 5; wgt = 2.f; }
    atomicAdd(&W[idx], wgt * ts);
  }
}

__global__ void combine_k(const float* __restrict__ W, float* __restrict__ out) {
  if (threadIdx.x == 0) {
    float nll = -W[0] / (float)B_ROWS;
    float mat = W[1] / (float)B_ROWS;
    float mmd = (W[3] + W[4] - W[5]) / ((float)B_ROWS * (float)B_ROWS);
    out[0] = 0.1f * nll + 0.001f * mat + 0.5f * mmd;
  }
}

extern "C" void kernel_launch(void* const* d_in, const int* in_sizes, int n_in,
                              void* d_out, int out_size, void* d_ws, size_t ws_size,
                              hipStream_t stream) {
  const float* pred   = (const float*)d_in[0];
  const int*   tgt    = (const int*)d_in[1];
  const float* trans  = (const float*)d_in[2];
  const float* dense  = (const float*)d_in[3];
  const float* sparse = (const float*)d_in[4];
  float* W = (float*)d_ws;
  unsigned short* tot = (unsigned short*)((char*)d_ws + WS_TOT_BYTE_OFF);
  float* out = (float*)d_out;

  init_k<<<dim3(5), dim3(256), 0, stream>>>(W);
  prep_k<<<dim3(256), dim3(256), 0, stream>>>(dense, sparse, W, tot);
  bw_k<<<dim3(1), dim3(256), 0, stream>>>(W);
  nll_k<<<dim3(16), dim3(256), 0, stream>>>(pred, tgt, W);
  matdiff_k<<<dim3(1024), dim3(256), 0, stream>>>(trans, W);
  gram_k<<<dim3(2080), dim3(256), 0, stream>>>(tot, W);
  combine_k<<<dim3(1), dim3(64), 0, stream>>>(W, out);
}

// Round 2
// 233.604 us; speedup vs baseline: 1.2411x; 1.1196x over previous
//
#include <hip/hip_runtime.h>
#include <math.h>

#define B_ROWS 4096
#define DIM    1024
#define NTOT   8192
#define NCLS   40
#define TILES2 32   // 8192 / 256
#define NBLK   528  // 32*33/2

typedef __attribute__((ext_vector_type(8))) short bf16x8;
typedef __attribute__((ext_vector_type(4))) float f32x4;

// ws layout (floats): [0]=nll_sum [1]=matdiff_sum [2]=sum_sq [3]=sxx [4]=syy
// [5]=smix(xy+yx) [6]=unused [7]=gram ticket counter ; [8..1032)=colsum[1024] ;
// [1032..9224)=sq[8192] ; byte 36896+ : bf16 total[8192*1024]
#define WS_TOT_BYTE_OFF 36896

__device__ __forceinline__ unsigned short f2bf(float f) {
  unsigned int u = __float_as_uint(f);
  u += 0x7fffu + ((u >> 16) & 1u);   // RNE
  return (unsigned short)(u >> 16);
}

__device__ __forceinline__ void async16(const void* g, void* l) {
  __builtin_amdgcn_global_load_lds(
      (const __attribute__((address_space(1))) unsigned int*)g,
      (__attribute__((address_space(3))) unsigned int*)l, 16, 0, 0);
}

__device__ __forceinline__ float wave_sum(float v) {
  v += __shfl_xor(v, 32);
  v += __shfl_xor(v, 16);
  v += __shfl_xor(v, 8);
  v += __shfl_xor(v, 4);
  v += __shfl_xor(v, 2);
  v += __shfl_xor(v, 1);
  return v;
}

__global__ void init_k(float* W) {
  int t = blockIdx.x * blockDim.x + threadIdx.x;
  if (t < 1032) W[t] = 0.f;   // scalars + ticket + colsum
}

// ---------------- fused pre: prep (256 blocks) + nll (16) + matdiff (1024) ---

__device__ void prep_body(int blk, const float* __restrict__ dense,
                          const float* __restrict__ sparse,
                          float* __restrict__ W,
                          unsigned short* __restrict__ tot) {
  float* colsum = W + 8;
  float* sq = W + 1032;
  const int t = threadIdx.x;
  const int lane = t & 63, wave = t >> 6;
  __shared__ float colsum_l[1024];
  #pragma unroll
  for (int x = 0; x < 4; ++x) colsum_l[t * 4 + x] = 0.f;

  float c[4][4];
  #pragma unroll
  for (int j = 0; j < 4; ++j)
    #pragma unroll
    for (int x = 0; x < 4; ++x) c[j][x] = 0.f;

  float rowtot = 0.f;
  const int rbase = blk * 32 + wave;   // 8 rows per wave, stride 4
  for (int i = 0; i < 8; ++i) {
    const int r = rbase + i * 4;
    const float* src = (r < B_ROWS) ? dense + (size_t)r * DIM
                                    : sparse + (size_t)(r - B_ROWS) * DIM;
    float sp = 0.f;
    #pragma unroll
    for (int j = 0; j < 4; ++j) {
      float4 v = ((const float4*)src)[lane + 64 * j];
      c[j][0] += v.x; c[j][1] += v.y; c[j][2] += v.z; c[j][3] += v.w;
      sp += v.x * v.x + v.y * v.y + v.z * v.z + v.w * v.w;
      ushort4 o;
      o.x = f2bf(v.x); o.y = f2bf(v.y); o.z = f2bf(v.z); o.w = f2bf(v.w);
      *(ushort4*)(tot + (size_t)r * DIM + (lane + 64 * j) * 4) = o;
    }
    sp = wave_sum(sp);
    if (lane == 0) { sq[r] = sp; rowtot += sp; }
  }
  if (lane == 0) atomicAdd(&W[2], rowtot);

  __syncthreads();
  #pragma unroll
  for (int j = 0; j < 4; ++j)
    #pragma unroll
    for (int x = 0; x < 4; ++x)
      atomicAdd(&colsum_l[4 * lane + 256 * j + x], c[j][x]);
  __syncthreads();
  #pragma unroll
  for (int x = 0; x < 4; ++x)
    atomicAdd(&colsum[t * 4 + x], colsum_l[t * 4 + x]);
}

__device__ void nll_body(int blk, const float* __restrict__ pred,
                         const int* __restrict__ tgt, float* __restrict__ W) {
  const int i = blk * 256 + threadIdx.x;
  float v = pred[(size_t)i * NCLS + tgt[i]];
  v = wave_sum(v);
  __shared__ float red[4];
  if ((threadIdx.x & 63) == 0) red[threadIdx.x >> 6] = v;
  __syncthreads();
  if (threadIdx.x == 0) atomicAdd(&W[0], red[0] + red[1] + red[2] + red[3]);
}

__device__ void matdiff_body(int blk, const float* __restrict__ trans,
                             float* __restrict__ W) {
  const int t = threadIdx.x;
  const int lane = t & 63, wave = t >> 6;
  const int b = blk * 4 + wave;
  const float* Tb = trans + (size_t)b * 4096;
  const int fr = lane & 15;
  const int k8 = (lane >> 4) * 8;
  bf16x8 frag[4][2];
  #pragma unroll
  for (int m = 0; m < 4; ++m) {
    #pragma unroll
    for (int kk = 0; kk < 2; ++kk) {
      const float* p = Tb + (size_t)(16 * m + fr) * 64 + kk * 32 + k8;
      float4 u0 = *(const float4*)p;
      float4 u1 = *(const float4*)(p + 4);
      bf16x8 f;
      f[0] = (short)f2bf(u0.x); f[1] = (short)f2bf(u0.y);
      f[2] = (short)f2bf(u0.z); f[3] = (short)f2bf(u0.w);
      f[4] = (short)f2bf(u1.x); f[5] = (short)f2bf(u1.y);
      f[6] = (short)f2bf(u1.z); f[7] = (short)f2bf(u1.w);
      frag[m][kk] = f;
    }
  }
  f32x4 acc[4][4];
  #pragma unroll
  for (int m = 0; m < 4; ++m)
    #pragma unroll
    for (int n = 0; n < 4; ++n) acc[m][n] = (f32x4)(0.f);
  #pragma unroll
  for (int kk = 0; kk < 2; ++kk)
    #pragma unroll
    for (int m = 0; m < 4; ++m)
      #pragma unroll
      for (int n = 0; n < 4; ++n)
        acc[m][n] = __builtin_amdgcn_mfma_f32_16x16x32_bf16(frag[m][kk], frag[n][kk],
                                                            acc[m][n], 0, 0, 0);
  float s = 0.f;
  const int crow = (lane >> 4) * 4;
  #pragma unroll
  for (int m = 0; m < 4; ++m)
    #pragma unroll
    for (int n = 0; n < 4; ++n)
      #pragma unroll
      for (int r = 0; r < 4; ++r) {
        int grow = 16 * m + crow + r;
        int gcol = 16 * n + fr;
        float g = acc[m][n][r];
        float d = (grow == gcol) ? (1.f - g) : (-g);
        s += d * d;
      }
  s = wave_sum(s);
  if (lane == 0) atomicAdd(&W[1], sqrtf(s));
}

__global__ __launch_bounds__(256) void fused_pre_k(
    const float* __restrict__ pred, const int* __restrict__ tgt,
    const float* __restrict__ trans, const float* __restrict__ dense,
    const float* __restrict__ sparse, float* __restrict__ W,
    unsigned short* __restrict__ tot) {
  const int blk = blockIdx.x;
  if (blk < 256)       prep_body(blk, dense, sparse, W, tot);
  else if (blk < 272)  nll_body(blk - 256, pred, tgt, W);
  else                 matdiff_body(blk - 272, trans, W);
}

// ---------------- gram: 256x256 tiles, 8 waves (2Mx4N), BK=64, dbuf LDS -------
// Raw-barrier pipeline: ONE barrier + vmcnt drain per K-tile; next-tile loads
// issued spread across the 4 phases so their latency hides under MFMA.
// T2 XOR-swizzle (rule #21: linear LDS dest + inverse-swizzled global source +
// swizzled read). cexp computed per-block (bw_k folded in); last block (ticket)
// does the final combine (combine_k folded in).
__global__ __launch_bounds__(512, 2) void gram_k(const unsigned short* __restrict__ tot,
                                                 float* __restrict__ W,
                                                 float* __restrict__ out) {
  __shared__ short As[2][16384];   // [buf][256 rows x 64 cols]
  __shared__ short Bs[2][16384];
  __shared__ float sqA[256], sqB[256], red[8];
  const float* sq = W + 1032;
  const float* colsum = W + 8;
  const int t = threadIdx.x;              // 0..511
  const int lane = t & 63, wave = t >> 6; // 8 waves
  const int wr = wave >> 2, wc = wave & 3;

  // T1: XCD-contiguous remap; 528 = 8*66 -> chunking bijective
  int p = (blockIdx.x & 7) * (NBLK / 8) + (blockIdx.x >> 3);

  // decode linear id -> (bi, bj), bi <= bj, T=32
  int bi = (int)((2 * TILES2 + 1 -
                  sqrtf((float)((2 * TILES2 + 1) * (2 * TILES2 + 1) - 8 * p))) * 0.5f);
  if (bi < 0) bi = 0;
  if (bi >= TILES2) bi = TILES2 - 1;
  int start = bi * (2 * TILES2 - bi + 1) / 2;
  while (p < start) { --bi; start = bi * (2 * TILES2 - bi + 1) / 2; }
  while (p >= start + (TILES2 - bi)) { start += TILES2 - bi; ++bi; }
  const int bj = bi + (p - start);

  // staging addresses: chunk = c*512+t ; row = chunk>>3 ; seg' = (chunk&7)^(row&7)
  const unsigned short* gA[4];
  const unsigned short* gB[4];
  int ldso[4];
  #pragma unroll
  for (int c = 0; c < 4; ++c) {
    int chunk = c * 512 + t;
    int row = chunk >> 3;
    int segp = (chunk & 7) ^ (row & 7);
    gA[c] = tot + (size_t)(bi * 256 + row) * DIM + segp * 8;
    gB[c] = tot + (size_t)(bj * 256 + row) * DIM + segp * 8;
    ldso[c] = chunk * 8;
  }

  // prologue: stage K-tiles 0 (buf0) and 1 (buf1) — 16 loads in flight
  #pragma unroll
  for (int c = 0; c < 4; ++c) { async16(gA[c], &As[0][ldso[c]]); async16(gB[c], &Bs[0][ldso[c]]); }
  #pragma unroll
  for (int c = 0; c < 4; ++c) { async16(gA[c] + 64, &As[1][ldso[c]]); async16(gB[c] + 64, &Bs[1][ldso[c]]); }

  // overlap with load latency: sq staging + per-wave bandwidth coefficient
  if (t < 256) sqA[t] = sq[bi * 256 + t];
  else         sqB[t - 256] = sq[bj * 256 + (t - 256)];
  float csp = 0.f;
  #pragma unroll
  for (int j = 0; j < 16; ++j) { float v = colsum[lane + 64 * j]; csp += v * v; }
  csp = wave_sum(csp);   // every wave holds full ||colsum||^2
  double sumdots = (double)csp;
  double sum_sq = (double)W[2];
  double sumL2 = 2.0 * (double)NTOT * sum_sq - 2.0 * sumdots;
  double bwv = sumL2 / ((double)NTOT * (double)NTOT - (double)NTOT);
  const float cexp16 = (float)(4.0 / bwv) * 0.0625f;  // c/16: widest kernel coeff

  f32x4 acc[8][4];
  #pragma unroll
  for (int m = 0; m < 8; ++m)
    #pragma unroll
    for (int n = 0; n < 4; ++n) acc[m][n] = (f32x4)(0.f);

  const int fr = lane & 15;
  const int hi16 = (lane >> 4) * 16;   // byte offset of the 8-elem k-slice
  const int swz = (fr & 7) << 4;

  // tile-0 data landed (8 newest = tile 1 stay in flight)
  asm volatile("s_waitcnt vmcnt(8)" ::: "memory");
  __builtin_amdgcn_s_barrier();
  asm volatile("" ::: "memory");

  for (int kt = 0; kt < 16; ++kt) {
    const int cur = kt & 1;
    const int nxt = cur ^ 1;
    const bool doStage = (kt >= 1 && kt < 15);   // tile kt+1 -> buf[nxt]
    const char* bA = (const char*)&As[cur][0];
    const char* bB = (const char*)&Bs[cur][0];

    if (doStage) {   // A panel of next tile, early
      #pragma unroll
      for (int c = 0; c < 4; ++c) async16(gA[c] + (kt + 1) * 64, &As[nxt][ldso[c]]);
    }

    bf16x8 a[8], b0, b1;
    // ---- ph0: kk0, n={0,1}
    #pragma unroll
    for (int m = 0; m < 8; ++m)
      a[m] = *(const bf16x8*)(bA + (wr * 128 + 16 * m + fr) * 128 + (hi16 ^ swz));
    b0 = *(const bf16x8*)(bB + (wc * 64 + 0 + fr) * 128 + (hi16 ^ swz));
    b1 = *(const bf16x8*)(bB + (wc * 64 + 16 + fr) * 128 + (hi16 ^ swz));
    __builtin_amdgcn_s_setprio(1);
    #pragma unroll
    for (int m = 0; m < 8; ++m) {
      acc[m][0] = __builtin_amdgcn_mfma_f32_16x16x32_bf16(a[m], b0, acc[m][0], 0, 0, 0);
      acc[m][1] = __builtin_amdgcn_mfma_f32_16x16x32_bf16(a[m], b1, acc[m][1], 0, 0, 0);
    }
    __builtin_amdgcn_s_setprio(0);
    if (doStage) {   // B panel low half
      async16(gB[0] + (kt + 1) * 64, &Bs[nxt][ldso[0]]);
      async16(gB[1] + (kt + 1) * 64, &Bs[nxt][ldso[1]]);
    }
    // ---- ph1: kk0, n={2,3}
    b0 = *(const bf16x8*)(bB + (wc * 64 + 32 + fr) * 128 + (hi16 ^ swz));
    b1 = *(const bf16x8*)(bB + (wc * 64 + 48 + fr) * 128 + (hi16 ^ swz));
    __builtin_amdgcn_s_setprio(1);
    #pragma unroll
    for (int m = 0; m < 8; ++m) {
      acc[m][2] = __builtin_amdgcn_mfma_f32_16x16x32_bf16(a[m], b0, acc[m][2], 0, 0, 0);
      acc[m][3] = __builtin_amdgcn_mfma_f32_16x16x32_bf16(a[m], b1, acc[m][3], 0, 0, 0);
    }
    __builtin_amdgcn_s_setprio(0);
    if (doStage) {   // B panel high half
      async16(gB[2] + (kt + 1) * 64, &Bs[nxt][ldso[2]]);
      async16(gB[3] + (kt + 1) * 64, &Bs[nxt][ldso[3]]);
    }
    // ---- ph2: kk1, n={0,1}
    #pragma unroll
    for (int m = 0; m < 8; ++m)
      a[m] = *(const bf16x8*)(bA + (wr * 128 + 16 * m + fr) * 128 + ((64 + hi16) ^ swz));
    b0 = *(const bf16x8*)(bB + (wc * 64 + 0 + fr) * 128 + ((64 + hi16) ^ swz));
    b1 = *(const bf16x8*)(bB + (wc * 64 + 16 + fr) * 128 + ((64 + hi16) ^ swz));
    __builtin_amdgcn_s_setprio(1);
    #pragma unroll
    for (int m = 0; m < 8; ++m) {
      acc[m][0] = __builtin_amdgcn_mfma_f32_16x16x32_bf16(a[m], b0, acc[m][0], 0, 0, 0);
      acc[m][1] = __builtin_amdgcn_mfma_f32_16x16x32_bf16(a[m], b1, acc[m][1], 0, 0, 0);
    }
    __builtin_amdgcn_s_setprio(0);
    // ---- ph3: kk1, n={2,3}
    b0 = *(const bf16x8*)(bB + (wc * 64 + 32 + fr) * 128 + ((64 + hi16) ^ swz));
    b1 = *(const bf16x8*)(bB + (wc * 64 + 48 + fr) * 128 + ((64 + hi16) ^ swz));
    __builtin_amdgcn_s_setprio(1);
    #pragma unroll
    for (int m = 0; m < 8; ++m) {
      acc[m][2] = __builtin_amdgcn_mfma_f32_16x16x32_bf16(a[m], b0, acc[m][2], 0, 0, 0);
      acc[m][3] = __builtin_amdgcn_mfma_f32_16x16x32_bf16(a[m], b1, acc[m][3], 0, 0, 0);
    }
    __builtin_amdgcn_s_setprio(0);

    if (kt < 15) {
      // drain next-tile loads (issued up to 4 phases ago) + workgroup barrier
      asm volatile("s_waitcnt vmcnt(0)" ::: "memory");
      __builtin_amdgcn_s_barrier();
      asm volatile("" ::: "memory");
    }
  }

  // epilogue: l2 -> 5-kernel sum. k_i = exp(-l2*c/2^i); exp of smallest,
  // then 4 squarings
  float s = 0.f;
  const int crow = (lane >> 4) * 4;
  #pragma unroll
  for (int m = 0; m < 8; ++m) {
    #pragma unroll
    for (int n = 0; n < 4; ++n) {
      #pragma unroll
      for (int r = 0; r < 4; ++r) {
        int il = wr * 128 + 16 * m + crow + r;
        int jl = wc * 64 + 16 * n + fr;
        float l2 = sqA[il] + sqB[jl] - 2.f * acc[m][n][r];
        l2 = fmaxf(l2, 0.f);
        float k4 = __expf(-l2 * cexp16);
        float k3 = k4 * k4;
        float k2 = k3 * k3;
        float k1 = k2 * k2;
        float k0 = k1 * k1;
        s += k0 + k1 + k2 + k3 + k4;
      }
    }
  }
  s = wave_sum(s);
  if (lane == 0) red[wave] = s;
  __syncthreads();
  if (t == 0) {
    float ts = 0.f;
    #pragma unroll
    for (int w = 0; w < 8; ++w) ts += red[w];
    int idx; float wgt;
    if (bi == bj)      { idx = (bi < 16) ? 3 : 4; wgt = 1.f; }
    else if (bj < 16)  { idx = 3; wgt = 2.f; }
    else if (bi >= 16) { idx = 4; wgt = 2.f; }
    else               { idx = 5; wgt = 2.f; }
    atomicAdd(&W[idx], wgt * ts);
    __threadfence();
    unsigned int tk = atomicAdd((unsigned int*)(W + 7), 1u);
    if (tk == NBLK - 1) {   // last block: final combine
      __threadfence();
      float nll = -*(volatile float*)(W + 0) / (float)B_ROWS;
      float mat =  *(volatile float*)(W + 1) / (float)B_ROWS;
      float sxx =  *(volatile float*)(W + 3);
      float syy =  *(volatile float*)(W + 4);
      float smx =  *(volatile float*)(W + 5);
      float mmd = (sxx + syy - smx) / ((float)B_ROWS * (float)B_ROWS);
      out[0] = 0.1f * nll + 0.001f * mat + 0.5f * mmd;
    }
  }
}

extern "C" void kernel_launch(void* const* d_in, const int* in_sizes, int n_in,
                              void* d_out, int out_size, void* d_ws, size_t ws_size,
                              hipStream_t stream) {
  const float* pred   = (const float*)d_in[0];
  const int*   tgt    = (const int*)d_in[1];
  const float* trans  = (const float*)d_in[2];
  const float* dense  = (const float*)d_in[3];
  const float* sparse = (const float*)d_in[4];
  float* W = (float*)d_ws;
  unsigned short* tot = (unsigned short*)((char*)d_ws + WS_TOT_BYTE_OFF);
  float* out = (float*)d_out;

  init_k<<<dim3(5), dim3(256), 0, stream>>>(W);
  fused_pre_k<<<dim3(1296), dim3(256), 0, stream>>>(pred, tgt, trans, dense, sparse, W, tot);
  gram_k<<<dim3(NBLK), dim3(512), 0, stream>>>(tot, W, out);
}

// Round 3
// 227.068 us; speedup vs baseline: 1.2769x; 1.0288x over previous
//
#include <hip/hip_runtime.h>
#include <math.h>

#define B_ROWS 4096
#define DIM    1024
#define NTOT   8192
#define NCLS   40
#define TILES2 32   // 8192 / 256
#define NBLK   528  // 32*33/2

typedef __attribute__((ext_vector_type(8))) short bf16x8;
typedef __attribute__((ext_vector_type(4))) float f32x4;

// ws layout (floats): [0]=nll_sum [1]=matdiff_sum [2]=sum_sq [3]=sxx [4]=syy
// [5]=smix(xy+yx) [6]=unused [7]=gram ticket counter ; [8..1032)=colsum[1024] ;
// [1032..9224)=sq[8192] ; byte 36896+ : bf16 total[8192*1024]
#define WS_TOT_BYTE_OFF 36896

#define FENCE() asm volatile("" ::: "memory")
#define BARRIER() do { FENCE(); __builtin_amdgcn_s_barrier(); FENCE(); } while (0)
#define MFMA16(d, x, y) d = __builtin_amdgcn_mfma_f32_16x16x32_bf16(x, y, d, 0, 0, 0)

__device__ __forceinline__ unsigned short f2bf(float f) {
  unsigned int u = __float_as_uint(f);
  u += 0x7fffu + ((u >> 16) & 1u);   // RNE
  return (unsigned short)(u >> 16);
}

__device__ __forceinline__ void async16(const void* g, void* l) {
  __builtin_amdgcn_global_load_lds(
      (const __attribute__((address_space(1))) unsigned int*)g,
      (__attribute__((address_space(3))) unsigned int*)l, 16, 0, 0);
}

__device__ __forceinline__ float wave_sum(float v) {
  v += __shfl_xor(v, 32);
  v += __shfl_xor(v, 16);
  v += __shfl_xor(v, 8);
  v += __shfl_xor(v, 4);
  v += __shfl_xor(v, 2);
  v += __shfl_xor(v, 1);
  return v;
}

__global__ void init_k(float* W) {
  int t = blockIdx.x * blockDim.x + threadIdx.x;
  if (t < 1032) W[t] = 0.f;   // scalars + ticket + colsum
}

// ---------------- fused pre: prep (256 blocks) + nll (16) + matdiff (1024) ---

__device__ void prep_body(int blk, const float* __restrict__ dense,
                          const float* __restrict__ sparse,
                          float* __restrict__ W,
                          unsigned short* __restrict__ tot) {
  float* colsum = W + 8;
  float* sq = W + 1032;
  const int t = threadIdx.x;
  const int lane = t & 63, wave = t >> 6;
  __shared__ float colsum_l[1024];
  #pragma unroll
  for (int x = 0; x < 4; ++x) colsum_l[t * 4 + x] = 0.f;

  float c[4][4];
  #pragma unroll
  for (int j = 0; j < 4; ++j)
    #pragma unroll
    for (int x = 0; x < 4; ++x) c[j][x] = 0.f;

  float rowtot = 0.f;
  const int rbase = blk * 32 + wave;   // 8 rows per wave, stride 4
  for (int i = 0; i < 8; ++i) {
    const int r = rbase + i * 4;
    const float* src = (r < B_ROWS) ? dense + (size_t)r * DIM
                                    : sparse + (size_t)(r - B_ROWS) * DIM;
    float sp = 0.f;
    #pragma unroll
    for (int j = 0; j < 4; ++j) {
      float4 v = ((const float4*)src)[lane + 64 * j];
      c[j][0] += v.x; c[j][1] += v.y; c[j][2] += v.z; c[j][3] += v.w;
      sp += v.x * v.x + v.y * v.y + v.z * v.z + v.w * v.w;
      ushort4 o;
      o.x = f2bf(v.x); o.y = f2bf(v.y); o.z = f2bf(v.z); o.w = f2bf(v.w);
      *(ushort4*)(tot + (size_t)r * DIM + (lane + 64 * j) * 4) = o;
    }
    sp = wave_sum(sp);
    if (lane == 0) { sq[r] = sp; rowtot += sp; }
  }
  if (lane == 0) atomicAdd(&W[2], rowtot);

  __syncthreads();
  #pragma unroll
  for (int j = 0; j < 4; ++j)
    #pragma unroll
    for (int x = 0; x < 4; ++x)
      atomicAdd(&colsum_l[4 * lane + 256 * j + x], c[j][x]);
  __syncthreads();
  #pragma unroll
  for (int x = 0; x < 4; ++x)
    atomicAdd(&colsum[t * 4 + x], colsum_l[t * 4 + x]);
}

__device__ void nll_body(int blk, const float* __restrict__ pred,
                         const int* __restrict__ tgt, float* __restrict__ W) {
  const int i = blk * 256 + threadIdx.x;
  float v = pred[(size_t)i * NCLS + tgt[i]];
  v = wave_sum(v);
  __shared__ float red[4];
  if ((threadIdx.x & 63) == 0) red[threadIdx.x >> 6] = v;
  __syncthreads();
  if (threadIdx.x == 0) atomicAdd(&W[0], red[0] + red[1] + red[2] + red[3]);
}

__device__ void matdiff_body(int blk, const float* __restrict__ trans,
                             float* __restrict__ W) {
  const int t = threadIdx.x;
  const int lane = t & 63, wave = t >> 6;
  const int b = blk * 4 + wave;
  const float* Tb = trans + (size_t)b * 4096;
  const int fr = lane & 15;
  const int k8 = (lane >> 4) * 8;
  bf16x8 frag[4][2];
  #pragma unroll
  for (int m = 0; m < 4; ++m) {
    #pragma unroll
    for (int kk = 0; kk < 2; ++kk) {
      const float* p = Tb + (size_t)(16 * m + fr) * 64 + kk * 32 + k8;
      float4 u0 = *(const float4*)p;
      float4 u1 = *(const float4*)(p + 4);
      bf16x8 f;
      f[0] = (short)f2bf(u0.x); f[1] = (short)f2bf(u0.y);
      f[2] = (short)f2bf(u0.z); f[3] = (short)f2bf(u0.w);
      f[4] = (short)f2bf(u1.x); f[5] = (short)f2bf(u1.y);
      f[6] = (short)f2bf(u1.z); f[7] = (short)f2bf(u1.w);
      frag[m][kk] = f;
    }
  }
  f32x4 acc[4][4];
  #pragma unroll
  for (int m = 0; m < 4; ++m)
    #pragma unroll
    for (int n = 0; n < 4; ++n) acc[m][n] = (f32x4)(0.f);
  #pragma unroll
  for (int kk = 0; kk < 2; ++kk)
    #pragma unroll
    for (int m = 0; m < 4; ++m)
      #pragma unroll
      for (int n = 0; n < 4; ++n)
        acc[m][n] = __builtin_amdgcn_mfma_f32_16x16x32_bf16(frag[m][kk], frag[n][kk],
                                                            acc[m][n], 0, 0, 0);
  float s = 0.f;
  const int crow = (lane >> 4) * 4;
  #pragma unroll
  for (int m = 0; m < 4; ++m)
    #pragma unroll
    for (int n = 0; n < 4; ++n)
      #pragma unroll
      for (int r = 0; r < 4; ++r) {
        int grow = 16 * m + crow + r;
        int gcol = 16 * n + fr;
        float g = acc[m][n][r];
        float d = (grow == gcol) ? (1.f - g) : (-g);
        s += d * d;
      }
  s = wave_sum(s);
  if (lane == 0) atomicAdd(&W[1], sqrtf(s));
}

__global__ __launch_bounds__(256) void fused_pre_k(
    const float* __restrict__ pred, const int* __restrict__ tgt,
    const float* __restrict__ trans, const float* __restrict__ dense,
    const float* __restrict__ sparse, float* __restrict__ W,
    unsigned short* __restrict__ tot) {
  const int blk = blockIdx.x;
  if (blk < 256)       prep_body(blk, dense, sparse, W, tot);
  else if (blk < 272)  nll_body(blk - 256, pred, tgt, W);
  else                 matdiff_body(blk - 272, trans, W);
}

// ---------------- gram: 256x256 tiles, 8 waves (2Mx4N), BK=64 -----------------
// k-PLANE split: each K-tile = two 16KB planes (kk0 = cols 0-31, kk1 = 32-63),
// LDS [buf][kk][256 rows x 32 cols].  Phases P0/P1 consume kk0, P2/P3 kk1 ->
// staging one plane per phase gives every load 3-4 phases of cover, and waits
// are counted vmcnt(4) (never 0 in main loop) — T3+T4.  Swizzle for 64B rows:
// slot' = slot ^ ((row>>1)&3)  (bank-group = 4(row&1)+slot' covers all 8 ->
// 2-way only).  Inverse swizzle applied at the global source (rule #21).
// Per phase: ds_read -> stage -> lgkmcnt(0)+sched_barrier -> setprio MFMA -> bar.
__global__ __launch_bounds__(512, 2) void gram_k(const unsigned short* __restrict__ tot,
                                                 float* __restrict__ W,
                                                 float* __restrict__ out) {
  __shared__ short As[2][2][8192];   // [buf][kk][256r x 32c] = 16KB per plane
  __shared__ short Bs[2][2][8192];
  __shared__ float sqA[256], sqB[256], red[8];
  const float* sq = W + 1032;
  const float* colsum = W + 8;
  const int t = threadIdx.x;              // 0..511
  const int lane = t & 63, wave = t >> 6; // 8 waves
  const int wr = wave >> 2, wc = wave & 3;

  // T1: XCD-contiguous remap; 528 = 8*66 -> chunking bijective
  int p = (blockIdx.x & 7) * (NBLK / 8) + (blockIdx.x >> 3);

  // decode linear id -> (bi, bj), bi <= bj, T=32
  int bi = (int)((2 * TILES2 + 1 -
                  sqrtf((float)((2 * TILES2 + 1) * (2 * TILES2 + 1) - 8 * p))) * 0.5f);
  if (bi < 0) bi = 0;
  if (bi >= TILES2) bi = TILES2 - 1;
  int start = bi * (2 * TILES2 - bi + 1) / 2;
  while (p < start) { --bi; start = bi * (2 * TILES2 - bi + 1) / 2; }
  while (p >= start + (TILES2 - bi)) { start += TILES2 - bi; ++bi; }
  const int bj = bi + (p - start);

  // staging: chunk = i*512+t ; r = chunk>>2 ; slot' = chunk&3 ;
  // global seg = slot' ^ ((r>>1)&3).  Second load = +128 rows.
  const int r0 = t >> 2;
  const int sg = (t & 3) ^ ((t >> 3) & 3);
  const size_t gA0 = (size_t)(bi * 256 + r0) * 1024 + sg * 8;
  const size_t gB0 = (size_t)(bj * 256 + r0) * 1024 + sg * 8;
  const int ldo = t * 8;   // shorts within plane

  auto stage = [&](size_t go, short* pl) {
    async16(tot + go, pl + ldo);
    async16(tot + go + 131072, pl + ldo + 4096);   // rows +128
  };

  // prologue: stage tile 0, planes in consumption order A0,B0,A1,B1 (8 loads)
  stage(gA0 +  0, &As[0][0][0]);
  stage(gB0 +  0, &Bs[0][0][0]);
  stage(gA0 + 32, &As[0][1][0]);
  stage(gB0 + 32, &Bs[0][1][0]);

  // overlap with load latency: sq staging + per-block bandwidth coefficient
  if (t < 256) sqA[t] = sq[bi * 256 + t];
  else         sqB[t - 256] = sq[bj * 256 + (t - 256)];
  float csp = 0.f;
  #pragma unroll
  for (int j = 0; j < 16; ++j) { float v = colsum[lane + 64 * j]; csp += v * v; }
  csp = wave_sum(csp);
  double sumdots = (double)csp;
  double sum_sq = (double)W[2];
  double sumL2 = 2.0 * (double)NTOT * sum_sq - 2.0 * sumdots;
  double bwv = sumL2 / ((double)NTOT * (double)NTOT - (double)NTOT);
  const float cexp16 = (float)(4.0 / bwv) * 0.0625f;  // c/16: widest kernel coeff

  f32x4 acc[8][4];
  #pragma unroll
  for (int m = 0; m < 8; ++m)
    #pragma unroll
    for (int n = 0; n < 4; ++n) acc[m][n] = (f32x4)(0.f);

  // ds_read addressing: row*64B + ((q ^ ((fr>>1)&3))<<4)
  const int q = lane >> 4;
  const int fr = lane & 15;
  const int rb = (q ^ ((fr >> 1) & 3)) << 4;
  const int aoff = (wr * 128 + fr) * 64 + rb;   // + m*1024 per m-frag
  const int boff = (wc * 64 + fr) * 64 + rb;    // + n*1024 per n-frag

  // A0,B0 of tile 0 landed (A1,B1 = newest 4 may stay in flight)
  asm volatile("s_waitcnt vmcnt(4)" ::: "memory");
  BARRIER();

  for (int kt = 0; kt < 16; ++kt) {
    const int cur = kt & 1, nxt = cur ^ 1;
    const bool st = (kt < 15);
    const size_t tb = (size_t)(kt + 1) * 64;
    const char* A0 = (const char*)&As[cur][0][0];
    const char* A1 = (const char*)&As[cur][1][0];
    const char* B0 = (const char*)&Bs[cur][0][0];
    const char* B1 = (const char*)&Bs[cur][1][0];

    bf16x8 aL[4], aH[4], b[4];

    // ---- P0: kk0, m=0..3 (first read of A0,B0 cur) ----
    #pragma unroll
    for (int m = 0; m < 4; ++m) aL[m] = *(const bf16x8*)(A0 + aoff + m * 1024);
    #pragma unroll
    for (int n = 0; n < 4; ++n) b[n] = *(const bf16x8*)(B0 + boff + n * 1024);
    if (st) stage(gA0 + tb, &As[nxt][0][0]);
    asm volatile("s_waitcnt lgkmcnt(0)" ::: "memory");
    __builtin_amdgcn_sched_barrier(0);
    __builtin_amdgcn_s_setprio(1);
    #pragma unroll
    for (int m = 0; m < 4; ++m)
      #pragma unroll
      for (int n = 0; n < 4; ++n) MFMA16(acc[m][n], aL[m], b[n]);
    __builtin_amdgcn_s_setprio(0);
    BARRIER();

    // ---- P1: kk0, m=4..7 (b[] reused from regs) ----
    #pragma unroll
    for (int m = 0; m < 4; ++m) aH[m] = *(const bf16x8*)(A0 + aoff + 4096 + m * 1024);
    if (st) stage(gB0 + tb, &Bs[nxt][0][0]);
    asm volatile("s_waitcnt lgkmcnt(0)" ::: "memory");
    __builtin_amdgcn_sched_barrier(0);
    __builtin_amdgcn_s_setprio(1);
    #pragma unroll
    for (int m = 0; m < 4; ++m)
      #pragma unroll
      for (int n = 0; n < 4; ++n) MFMA16(acc[4 + m][n], aH[m], b[n]);
    __builtin_amdgcn_s_setprio(0);
    // retire A1,B1(cur) before P2 reads them; keep A0,B0(nxt) in flight
    if (kt == 15) asm volatile("s_waitcnt vmcnt(0)" ::: "memory");
    else          asm volatile("s_waitcnt vmcnt(4)" ::: "memory");
    BARRIER();

    // ---- P2: kk1, m=0..3 (first read of A1,B1 cur) ----
    #pragma unroll
    for (int m = 0; m < 4; ++m) aL[m] = *(const bf16x8*)(A1 + aoff + m * 1024);
    #pragma unroll
    for (int n = 0; n < 4; ++n) b[n] = *(const bf16x8*)(B1 + boff + n * 1024);
    if (st) stage(gA0 + tb + 32, &As[nxt][1][0]);
    asm volatile("s_waitcnt lgkmcnt(0)" ::: "memory");
    __builtin_amdgcn_sched_barrier(0);
    __builtin_amdgcn_s_setprio(1);
    #pragma unroll
    for (int m = 0; m < 4; ++m)
      #pragma unroll
      for (int n = 0; n < 4; ++n) MFMA16(acc[m][n], aL[m], b[n]);
    __builtin_amdgcn_s_setprio(0);
    BARRIER();

    // ---- P3: kk1, m=4..7 ----
    #pragma unroll
    for (int m = 0; m < 4; ++m) aH[m] = *(const bf16x8*)(A1 + aoff + 4096 + m * 1024);
    if (st) stage(gB0 + tb + 32, &Bs[nxt][1][0]);
    asm volatile("s_waitcnt lgkmcnt(0)" ::: "memory");
    __builtin_amdgcn_sched_barrier(0);
    __builtin_amdgcn_s_setprio(1);
    #pragma unroll
    for (int m = 0; m < 4; ++m)
      #pragma unroll
      for (int n = 0; n < 4; ++n) MFMA16(acc[4 + m][n], aH[m], b[n]);
    __builtin_amdgcn_s_setprio(0);
    // retire A0,B0(kt+1) before next P0 reads them; keep A1,B1(kt+1) in flight
    if (kt == 15) asm volatile("s_waitcnt vmcnt(0)" ::: "memory");
    else          asm volatile("s_waitcnt vmcnt(4)" ::: "memory");
    BARRIER();
  }

  // epilogue: l2 -> 5-kernel sum. k_i = exp(-l2*c/2^i); exp of smallest,
  // then 4 squarings
  float s = 0.f;
  const int crow = (lane >> 4) * 4;
  #pragma unroll
  for (int m = 0; m < 8; ++m) {
    #pragma unroll
    for (int n = 0; n < 4; ++n) {
      #pragma unroll
      for (int r = 0; r < 4; ++r) {
        int il = wr * 128 + 16 * m + crow + r;
        int jl = wc * 64 + 16 * n + fr;
        float l2 = sqA[il] + sqB[jl] - 2.f * acc[m][n][r];
        l2 = fmaxf(l2, 0.f);
        float k4 = __expf(-l2 * cexp16);
        float k3 = k4 * k4;
        float k2 = k3 * k3;
        float k1 = k2 * k2;
        float k0 = k1 * k1;
        s += k0 + k1 + k2 + k3 + k4;
      }
    }
  }
  s = wave_sum(s);
  if (lane == 0) red[wave] = s;
  __syncthreads();
  if (t == 0) {
    float ts = 0.f;
    #pragma unroll
    for (int w = 0; w < 8; ++w) ts += red[w];
    int idx; float wgt;
    if (bi == bj)      { idx = (bi < 16) ? 3 : 4; wgt = 1.f; }
    else if (bj < 16)  { idx = 3; wgt = 2.f; }
    else if (bi >= 16) { idx = 4; wgt = 2.f; }
    else               { idx = 5; wgt = 2.f; }
    atomicAdd(&W[idx], wgt * ts);
    __threadfence();
    unsigned int tk = atomicAdd((unsigned int*)(W + 7), 1u);
    if (tk == NBLK - 1) {   // last block: final combine
      __threadfence();
      float nll = -*(volatile float*)(W + 0) / (float)B_ROWS;
      float mat =  *(volatile float*)(W + 1) / (float)B_ROWS;
      float sxx =  *(volatile float*)(W + 3);
      float syy =  *(volatile float*)(W + 4);
      float smx =  *(volatile float*)(W + 5);
      float mmd = (sxx + syy - smx) / ((float)B_ROWS * (float)B_ROWS);
      out[0] = 0.1f * nll + 0.001f * mat + 0.5f * mmd;
    }
  }
}

extern "C" void kernel_launch(void* const* d_in, const int* in_sizes, int n_in,
                              void* d_out, int out_size, void* d_ws, size_t ws_size,
                              hipStream_t stream) {
  const float* pred   = (const float*)d_in[0];
  const int*   tgt    = (const int*)d_in[1];
  const float* trans  = (const float*)d_in[2];
  const float* dense  = (const float*)d_in[3];
  const float* sparse = (const float*)d_in[4];
  float* W = (float*)d_ws;
  unsigned short* tot = (unsigned short*)((char*)d_ws + WS_TOT_BYTE_OFF);
  float* out = (float*)d_out;

  init_k<<<dim3(5), dim3(256), 0, stream>>>(W);
  fused_pre_k<<<dim3(1296), dim3(256), 0, stream>>>(pred, tgt, trans, dense, sparse, W, tot);
  gram_k<<<dim3(NBLK), dim3(512), 0, stream>>>(tot, W, out);
}